// Round 19
// baseline (592.169 us; speedup 1.0000x reference)
//
#include <hip/hip_runtime.h>
#include <cstdint>

typedef unsigned short u16;
typedef __attribute__((ext_vector_type(8))) short short8;   // 8 x bf16 (4 VGPR)
typedef __attribute__((ext_vector_type(4))) short short4v;  // 4 x bf16
typedef __attribute__((ext_vector_type(4))) float floatx4;  // MFMA acc / float4

#define DEV __device__ __forceinline__

DEV float bf2f(u16 u) { union { uint32_t i; float f; } w; w.i = ((uint32_t)u) << 16; return w.f; }
DEV u16 f2bf(float f) {
  union { float f; uint32_t i; } w; w.f = f;
  uint32_t x = w.i;
  return (u16)((x + 0x7fffu + ((x >> 16) & 1u)) >> 16);  // RNE
}

// packed chunk-major element offset: tile(row>>7, k>>5) of 128x32, 4096 elems,
// inner [c=(k>>3)&3][row&127][k&7]  (r10-proven conflict-free for MFMA frags)
DEV size_t poff(int row, int k, int nkt) {
  return ((size_t)((row >> 7) * nkt + (k >> 5))) * 4096 +
         (size_t)(((k >> 3) & 3) * 1024 + (row & 127) * 8 + (k & 7));
}

// fast exact-gelu: A&S 7.1.26 erf approx, |err|<=1.5e-7, branchless
DEV float fast_gelu(float x) {
  const float y = x * 0.70710678118f;
  const float ay = fabsf(y);
  const float t = 1.f / (1.f + 0.3275911f * ay);
  const float poly = t * (0.254829592f + t * (-0.284496736f +
                     t * (1.421413741f + t * (-1.453152027f + t * 1.061405429f))));
  const float er = 1.f - poly * __expf(-y * y);
  const float erf_y = __builtin_copysignf(er, y);
  return 0.5f * x * (1.f + erf_y);
}

// async global->LDS, 16B per lane. LDS dest must be wave-uniform base; HW adds lane*16.
DEV void async_copy16(const u16* g, u16* l) {
  __builtin_amdgcn_global_load_lds(
      (const __attribute__((address_space(1))) void*)(uintptr_t)g,
      (__attribute__((address_space(3))) void*)(uint32_t)(uintptr_t)l,
      16, 0, 0);
}

// ---------------- fused f32 -> bf16 weight convert, PACKED chunk-major ----------------
struct CvtArgs {
  const float* src[10];
  float scale[10];
};
__global__ __launch_bounds__(256) void cvt_all(CvtArgs a, u16* __restrict__ dst) {
  const size_t e = ((size_t)blockIdx.x * 256 + threadIdx.x) * 4;  // packed dest offset
  if (e >= 9437184) return;
  int reg, N, K;
  size_t base;
  if (e < 4718592) { reg = (int)(e / 589824); base = (size_t)reg * 589824; N = 768; K = 768; }
  else if (e < 7077888) { reg = 8; base = 4718592; N = 3072; K = 768; }
  else { reg = 9; base = 7077888; N = 768; K = 3072; }
  const int NKT = K >> 5;
  const size_t r = e - base;
  const int tile = (int)(r >> 12);
  const int nt = tile / NKT, kt = tile - nt * NKT;
  const int rem = (int)(r & 4095);
  const int c = rem >> 10, row = (rem >> 3) & 127, j = rem & 7;  // j in {0,4}
  const int n = nt * 128 + row, k = kt * 32 + c * 8 + j;
  const float sc = a.scale[reg];
  floatx4 f = *(const floatx4*)(a.src[reg] + (size_t)n * K + k);
  short4v o;
#pragma unroll
  for (int q = 0; q < 4; ++q) o[q] = (short)f2bf(f[q] * sc);
  *(short4v*)(dst + e) = o;
}

// pack q/k/v biases into one [2304] f32 buffer per stage, q part pre-scaled
__global__ __launch_bounds__(256) void bias_pack(const float* __restrict__ qb,
                                                 const float* __restrict__ kb,
                                                 const float* __restrict__ vb,
                                                 float sq, float* __restrict__ out) {
  const int i = blockIdx.x * 256 + threadIdx.x;
  if (i >= 2304) return;
  const int buf = i / 768, c = i - buf * 768;
  out[i] = buf == 0 ? qb[c] * sq : (buf == 1 ? kb[c] : vb[c]);
}

// ---------------- LayerNorm: 4 rows/block, PACKED out via LDS re-staging ----------------
template<bool INF32>
__global__ __launch_bounds__(256) void ln_kernel(const void* __restrict__ in,
                                                 const float* __restrict__ w,
                                                 const float* __restrict__ b,
                                                 u16* __restrict__ out) {
  __shared__ u16 S[4][768];
  const int wid = threadIdx.x >> 6, lane = threadIdx.x & 63;
  const int row0 = blockIdx.x * 4;
  const int row = row0 + wid;  // 16384 rows
  const size_t base = (size_t)row * 768;
  float v[12];
#pragma unroll
  for (int p = 0; p < 3; ++p) {
    const int e = p * 256 + lane * 4;
    if constexpr (INF32) {
      floatx4 f = *(const floatx4*)((const float*)in + base + e);
#pragma unroll
      for (int j = 0; j < 4; ++j) v[p * 4 + j] = f[j];
    } else {
      short4v u = *(const short4v*)((const u16*)in + base + e);
#pragma unroll
      for (int j = 0; j < 4; ++j) v[p * 4 + j] = bf2f((u16)u[j]);
    }
  }
  float s = 0.f, sq = 0.f;
#pragma unroll
  for (int i = 0; i < 12; ++i) { s += v[i]; sq += v[i] * v[i]; }
#pragma unroll
  for (int m = 1; m < 64; m <<= 1) { s += __shfl_xor(s, m); sq += __shfl_xor(sq, m); }
  const float mean = s * (1.f / 768.f);
  const float var = sq * (1.f / 768.f) - mean * mean;
  const float rstd = rsqrtf(var + 1e-5f);
#pragma unroll
  for (int p = 0; p < 3; ++p) {
    const int e = p * 256 + lane * 4;
    floatx4 wv = *(const floatx4*)(w + e);
    floatx4 bv = *(const floatx4*)(b + e);
    short4v o;
#pragma unroll
    for (int j = 0; j < 4; ++j) {
      float y = (v[p * 4 + j] - mean) * rstd * wv[j] + bv[j];
      o[j] = (short)f2bf(y);
    }
    *(short4v*)&S[wid][e] = o;
  }
  __syncthreads();
  const int t = threadIdx.x;
  {
    const int ro = t & 3, c = t >> 2;                     // c 0..63
    *(short8*)(out + poff(row0 + ro, c * 8, 24)) = *(const short8*)&S[ro][c * 8];
  }
  if (t < 128) {
    const int idx = 256 + t;
    const int ro = idx & 3, c = idx >> 2;                 // c 64..95
    *(short8*)(out + poff(row0 + ro, c * 8, 24)) = *(const short8*)&S[ro][c * 8];
  }
}

// ---------------- GEMM: 128x128, r15/r17 proven; NEW: optional XCD swizzle ----------------
// SWZ=1 (requires nwg%8==0, grid.z==1): bijective chunked remap so XCD j owns a
// contiguous x-range (16 A-panels = 3.1MB, fits its 4MB L2): A-panel reuse
// becomes L2-local instead of refetched per XCD (T1, m204 bijective form).
template<int AMODE, int AP, int BP>
DEV void stage_tile(const u16* __restrict__ Asrc, const u16* __restrict__ Bsrc,
                    int m0, int n0, int lda, int ldb, int kk0, int ktAbs, int t,
                    u16* ldsA, u16* ldsB) {
  const int wid = t >> 6, lane = t & 63;
  const int col = (((t & 3) ^ ((t >> 2) & 3)) << 3);
#pragma unroll
  for (int i = 0; i < 2; ++i) {
    const int slot = i * 4 + wid;
    const int r = i * 64 + (t >> 2);
    const int kk = kk0 + col;
    if constexpr (AP) {
      async_copy16(Asrc + (size_t)ktAbs * 4096 + slot * 512 + lane * 8, ldsA + slot * 512);
    } else {
      const u16* ga;
      if constexpr (AMODE == 0) {
        ga = Asrc + (size_t)(m0 + r) * lda + kk;
      } else {
        const int r96 = kk / 96, d = kk - r96 * 96;  // 8|96: chunk never crosses r96
        ga = Asrc + (size_t)r96 * 196608 + (size_t)(m0 + r) * 768 + d;
      }
      async_copy16(ga, ldsA + i * 2048 + wid * 512);
    }
    if constexpr (BP) {
      async_copy16(Bsrc + (size_t)ktAbs * 4096 + slot * 512 + lane * 8, ldsB + slot * 512);
    } else {
      const u16* gb;
      if constexpr (AMODE == 0) {
        gb = Bsrc + (size_t)(n0 + r) * ldb + kk;
      } else {
        const int r96 = kk / 96, d = kk - r96 * 96;
        gb = Bsrc + (size_t)r96 * 196608 + (size_t)(n0 + r) * 768 + d;
      }
      async_copy16(gb, ldsB + i * 2048 + wid * 512);
    }
  }
}

template<int AMODE, int EPI, int AP, int BP, int SWZ>
__global__ __launch_bounds__(256) void gemm_bt(
    const u16* __restrict__ A, const u16* __restrict__ B,
    const float* __restrict__ bias, const void* __restrict__ res,
    void* __restrict__ out, int K, int lda, int ldb,
    long long aBatch, long long bBatch, long long outBatch, int ldc, int bkt0,
    float scale) {
  __shared__ u16 lds[3 * 8192];  // 3 x (A 128x32 + B 128x32) = 48KB
  const int t = threadIdx.x;
  const int z = blockIdx.z;
  int bx = blockIdx.x, by = blockIdx.y;
  if constexpr (SWZ) {
    const int nwg = gridDim.x * gridDim.y;
    const int bid = by * gridDim.x + bx;
    const int work = (bid & 7) * (nwg >> 3) + (bid >> 3);  // bijective (nwg%8==0)
    bx = work / gridDim.y;                                 // x contiguous per XCD
    by = work - bx * gridDim.y;
  }
  const int m0 = bx * 128, n0 = by * 128;
  const u16* Ab;
  const u16* Bb;
  int koff = 0;
  if constexpr (AMODE == 0) { Ab = A + (size_t)z * aBatch; Bb = B + (size_t)z * bBatch; }
  else { const int h = z >> 4; Ab = A + h * 96; Bb = B + h * 96; koff = (z & 15) * 384; }

  const u16* Astage;
  const u16* Bstage;
  if constexpr (AP) Astage = Ab + ((size_t)((m0 >> 7) * lda)) * 4096;
  else Astage = Ab;
  if constexpr (BP) Bstage = Bb + ((size_t)((n0 >> 7) * ldb + bkt0)) * 4096;
  else Bstage = Bb;

  const int wid = t >> 6, lane = t & 63;
  const int wr = wid >> 1, wc = wid & 1;
  const int lrow = lane & 15, lhi = lane >> 4;
  const int swl = lrow & 3;

  floatx4 acc[4][4];
#pragma unroll
  for (int i = 0; i < 4; ++i)
#pragma unroll
    for (int j = 0; j < 4; ++j) acc[i][j] = (floatx4){0.f, 0.f, 0.f, 0.f};

  const int NT = K >> 5;

  stage_tile<AMODE, AP, BP>(Astage, Bstage, m0, n0, lda, ldb, koff, 0, t, lds, lds + 4096);
  if (NT > 1)
    stage_tile<AMODE, AP, BP>(Astage, Bstage, m0, n0, lda, ldb, koff + 32, 1, t,
                              lds + 8192, lds + 8192 + 4096);
  if (NT > 2) asm volatile("s_waitcnt vmcnt(4)" ::: "memory");
  else        asm volatile("s_waitcnt vmcnt(0)" ::: "memory");
  __builtin_amdgcn_s_barrier();
  asm volatile("" ::: "memory");

  int cur = 0, nxt = 2;
  for (int kt = 0; kt < NT; ++kt) {
    const bool more = (kt + 2) < NT;
    if (more)
      stage_tile<AMODE, AP, BP>(Astage, Bstage, m0, n0, lda, ldb, koff + (kt + 2) * 32,
                                kt + 2, t, lds + nxt * 8192, lds + nxt * 8192 + 4096);

    const u16* lA = lds + cur * 8192;
    const u16* lB = lA + 4096;
    short8 af[4], bfr[4];
#pragma unroll
    for (int mi = 0; mi < 4; ++mi) {
      if constexpr (AP)
        af[mi] = *(const short8*)&lA[lhi * 1024 + (wr * 64 + mi * 16 + lrow) * 8];
      else
        af[mi] = *(const short8*)&lA[(wr * 64 + mi * 16 + lrow) * 32 + ((lhi ^ swl) << 3)];
    }
#pragma unroll
    for (int ni = 0; ni < 4; ++ni) {
      if constexpr (BP)
        bfr[ni] = *(const short8*)&lB[lhi * 1024 + (wc * 64 + ni * 16 + lrow) * 8];
      else
        bfr[ni] = *(const short8*)&lB[(wc * 64 + ni * 16 + lrow) * 32 + ((lhi ^ swl) << 3)];
    }

    __builtin_amdgcn_s_setprio(1);
#pragma unroll
    for (int mi = 0; mi < 4; ++mi)
#pragma unroll
      for (int ni = 0; ni < 4; ++ni)
        acc[mi][ni] = __builtin_amdgcn_mfma_f32_16x16x32_bf16(af[mi], bfr[ni], acc[mi][ni], 0, 0, 0);
    __builtin_amdgcn_s_setprio(0);

    if (kt + 1 < NT) {
      if (more) asm volatile("s_waitcnt vmcnt(4)" ::: "memory");
      else      asm volatile("s_waitcnt vmcnt(0)" ::: "memory");
      __builtin_amdgcn_s_barrier();
      asm volatile("" ::: "memory");
    }
    cur = (cur == 2) ? 0 : cur + 1;
    nxt = (nxt == 2) ? 0 : nxt + 1;
  }

  const int mbase = m0 + wr * 64;
  const int nbase = n0 + wc * 64;
#pragma unroll
  for (int mi = 0; mi < 4; ++mi) {
#pragma unroll
    for (int ni = 0; ni < 4; ++ni) {
      const int n = nbase + ni * 16 + lrow;
      float bz = 0.f;
      if constexpr (EPI != 1 && EPI != 7) { if (bias) bz = bias[n]; }
#pragma unroll
      for (int r4 = 0; r4 < 4; ++r4) {
        const int m = mbase + mi * 16 + lhi * 4 + r4;
        const float val = acc[mi][ni][r4];
        if constexpr (EPI == 1) {
          ((float*)out)[(size_t)z * outBatch + (size_t)m * ldc + n] = val;
        } else if constexpr (EPI == 2) {
          ((u16*)out)[poff(m, n, ldc >> 5)] = f2bf(fast_gelu(val + bz));
        } else if constexpr (EPI == 3) {
          const float r = ((const float*)res)[(size_t)m * ldc + n];
          ((float*)out)[(size_t)m * ldc + n] = r + val + bz;
        } else if constexpr (EPI == 4) {
          const float r = ((const float*)res)[(size_t)m * ldc + n];
          ((u16*)out)[(size_t)m * ldc + n] = f2bf(r + val + bz);
        } else if constexpr (EPI == 7) {
          const int rr = n / 96, d = n - rr * 96;
          ((u16*)out)[poff(rr * 256 + m, z * 96 + d, 24)] = f2bf(val);
        } else if constexpr (EPI == 8) {
          const int buf = n / 768, col = n - buf * 768;
          ((u16*)out)[(size_t)buf * 12582912 + (size_t)m * 768 + col] = f2bf(val + bz);
        }
      }
    }
  }
}

// ---------------- row softmax fused with split-K reduce; PACKED probsb ----------------
__global__ __launch_bounds__(256) void softmax_row(const float* __restrict__ part,
                                                   float* __restrict__ probs_f,
                                                   u16* __restrict__ probs_b) {
  const int wid = threadIdx.x >> 6, lane = threadIdx.x & 63;
  const int row = blockIdx.x * 4 + wid;
  const int h = row >> 8, i = row & 255;
  const size_t base = (size_t)h * 16 * 65536 + (size_t)i * 256 + lane * 4;
  floatx4 v = (floatx4){0.f, 0.f, 0.f, 0.f};
#pragma unroll
  for (int s16 = 0; s16 < 16; ++s16) {
    floatx4 p = *(const floatx4*)(part + base + (size_t)s16 * 65536);
#pragma unroll
    for (int j = 0; j < 4; ++j) v[j] += p[j];
  }
  float mx = fmaxf(fmaxf(v[0], v[1]), fmaxf(v[2], v[3]));
#pragma unroll
  for (int m = 1; m < 64; m <<= 1) mx = fmaxf(mx, __shfl_xor(mx, m));
  float e[4], s = 0.f;
#pragma unroll
  for (int j = 0; j < 4; ++j) { e[j] = __expf(v[j] - mx); s += e[j]; }
#pragma unroll
  for (int m = 1; m < 64; m <<= 1) s += __shfl_xor(s, m);
  const float inv = 1.f / s;
  floatx4 of;
  short4v ob;
#pragma unroll
  for (int j = 0; j < 4; ++j) {
    const float p = e[j] * inv;
    of[j] = p;
    ob[j] = (short)f2bf(p);
  }
  *(floatx4*)(probs_f + (size_t)row * 256 + lane * 4) = of;
  *(short4v*)(probs_b + (size_t)h * 65536 + poff(i, lane * 4, 8)) = ob;
}

// ---------------- pack V^T for row-attn PV, PACKED chunk-major ----------------
__global__ __launch_bounds__(256) void pack_vt(const u16* __restrict__ v, u16* __restrict__ vt) {
  __shared__ u16 S[64][104];  // [j][d], padded
  const int jb = blockIdx.x, r = blockIdx.y, h = blockIdx.z;
  const int t = threadIdx.x;
#pragma unroll
  for (int p = 0; p < 3; ++p) {
    const int cid = t + p * 256;
    const int j = cid / 12, ch = cid - j * 12;
    short8 x = *(const short8*)&v[((size_t)(r * 256 + jb * 64 + j)) * 768 + h * 96 + ch * 8];
    *(short8*)&S[j][ch * 8] = x;
  }
  __syncthreads();
#pragma unroll
  for (int p = 0; p < 3; ++p) {
    const int cid = t + p * 256;
    const int d = cid / 8, cj = cid - d * 8;
    u16 tmp[8];
#pragma unroll
    for (int m = 0; m < 8; ++m) tmp[m] = S[cj * 8 + m][d];
    const int row_t = r * 96 + d;
    const int k = jb * 64 + cj * 8;
    *(short8*)&vt[(size_t)h * 1572864 + poff(row_t, k, 8)] = *(short8*)tmp;
  }
}

// ---------------- fused column attention: one block per (c, h); PACKED ctx ----------
__global__ __launch_bounds__(256) void col_attn(const u16* __restrict__ q,
                                                const u16* __restrict__ k,
                                                const u16* __restrict__ v,
                                                float* __restrict__ probs,
                                                u16* __restrict__ ctx) {
  __shared__ u16 qs[64][104];
  __shared__ u16 ks[64][104];
  __shared__ u16 vt[96][72];
  __shared__ u16 ps[64][72];
  const int c = blockIdx.x, h = blockIdx.y;
  const int t = threadIdx.x;
#pragma unroll
  for (int p = 0; p < 3; ++p) {
    const int cid = t + p * 256;
    const int i = cid / 12, ch = cid - i * 12;
    const size_t g = ((size_t)(i * 256 + c)) * 768 + h * 96 + ch * 8;
    short8 qv = *(const short8*)(q + g);
    short8 kv = *(const short8*)(k + g);
    short8 vv = *(const short8*)(v + g);
    *(short8*)&qs[i][ch * 8] = qv;
    *(short8*)&ks[i][ch * 8] = kv;
#pragma unroll
    for (int m = 0; m < 8; ++m) vt[ch * 8 + m][i] = (u16)vv[m];
  }
  __syncthreads();
  const int lane = t & 63, wid = t >> 6;
  const int lrow = lane & 15, lhi = lane >> 4;

  floatx4 s[4];
#pragma unroll
  for (int nj = 0; nj < 4; ++nj) s[nj] = (floatx4){0.f, 0.f, 0.f, 0.f};
#pragma unroll
  for (int kk = 0; kk < 3; ++kk) {
    short8 a = *(const short8*)&qs[wid * 16 + lrow][kk * 32 + lhi * 8];
#pragma unroll
    for (int nj = 0; nj < 4; ++nj) {
      short8 bb = *(const short8*)&ks[nj * 16 + lrow][kk * 32 + lhi * 8];
      s[nj] = __builtin_amdgcn_mfma_f32_16x16x32_bf16(a, bb, s[nj], 0, 0, 0);
    }
  }
  const size_t pb = ((size_t)(h * 256 + c)) * 4096;
#pragma unroll
  for (int r4 = 0; r4 < 4; ++r4) {
    float mx = fmaxf(fmaxf(s[0][r4], s[1][r4]), fmaxf(s[2][r4], s[3][r4]));
    mx = fmaxf(mx, __shfl_xor(mx, 1));
    mx = fmaxf(mx, __shfl_xor(mx, 2));
    mx = fmaxf(mx, __shfl_xor(mx, 4));
    mx = fmaxf(mx, __shfl_xor(mx, 8));
    float e[4], sum = 0.f;
#pragma unroll
    for (int nj = 0; nj < 4; ++nj) { e[nj] = __expf(s[nj][r4] - mx); sum += e[nj]; }
    sum += __shfl_xor(sum, 1);
    sum += __shfl_xor(sum, 2);
    sum += __shfl_xor(sum, 4);
    sum += __shfl_xor(sum, 8);
    const float inv = 1.f / sum;
    const int i = wid * 16 + lhi * 4 + r4;
#pragma unroll
    for (int nj = 0; nj < 4; ++nj) {
      const float pv = e[nj] * inv;
      const int j = nj * 16 + lrow;
      probs[pb + (size_t)i * 64 + j] = pv;
      ps[i][j] = f2bf(pv);
    }
  }
  __syncthreads();
  floatx4 o[6];
#pragma unroll
  for (int df = 0; df < 6; ++df) o[df] = (floatx4){0.f, 0.f, 0.f, 0.f};
#pragma unroll
  for (int k2 = 0; k2 < 2; ++k2) {
    short8 a = *(const short8*)&ps[wid * 16 + lrow][k2 * 32 + lhi * 8];
#pragma unroll
    for (int df = 0; df < 6; ++df) {
      short8 bb = *(const short8*)&vt[df * 16 + lrow][k2 * 32 + lhi * 8];
      o[df] = __builtin_amdgcn_mfma_f32_16x16x32_bf16(a, bb, o[df], 0, 0, 0);
    }
  }
#pragma unroll
  for (int df = 0; df < 6; ++df)
#pragma unroll
    for (int r4 = 0; r4 < 4; ++r4) {
      const int i = wid * 16 + lhi * 4 + r4;
      const int d = df * 16 + lrow;
      ctx[poff(i * 256 + c, h * 96 + d, 24)] = f2bf(o[df][r4]);  // packed ctx2
    }
}

// ---------------- host launch ----------------
extern "C" void kernel_launch(void* const* d_in, const int* in_sizes, int n_in,
                              void* d_out, int out_size, void* d_ws, size_t ws_size,
                              hipStream_t stream) {
  const float* x_in  = (const float*)d_in[0];
  const float* lnr_w = (const float*)d_in[1];
  const float* lnr_b = (const float*)d_in[2];
  const float* rq_w  = (const float*)d_in[3];
  const float* rq_b  = (const float*)d_in[4];
  const float* rk_w  = (const float*)d_in[5];
  const float* rk_b  = (const float*)d_in[6];
  const float* rv_w  = (const float*)d_in[7];
  const float* rv_b  = (const float*)d_in[8];
  const float* ro_w  = (const float*)d_in[9];
  const float* ro_b  = (const float*)d_in[10];
  const float* lnc_w = (const float*)d_in[11];
  const float* lnc_b = (const float*)d_in[12];
  const float* cq_w  = (const float*)d_in[13];
  const float* cq_b  = (const float*)d_in[14];
  const float* ck_w  = (const float*)d_in[15];
  const float* ck_b  = (const float*)d_in[16];
  const float* cv_w  = (const float*)d_in[17];
  const float* cv_b  = (const float*)d_in[18];
  const float* co_w  = (const float*)d_in[19];
  const float* co_b  = (const float*)d_in[20];
  const float* lnf_w = (const float*)d_in[21];
  const float* lnf_b = (const float*)d_in[22];
  const float* f1_w  = (const float*)d_in[23];
  const float* f1_b  = (const float*)d_in[24];
  const float* f2_w  = (const float*)d_in[25];
  const float* f2_b  = (const float*)d_in[26];

  const float s_row = 0.0127577591f;  // (96^-0.5)/8
  const float s_col = 0.1020620726f;  // 96^-0.5

  // ---- ws layout ----
  char* ws = (char*)d_ws;
  const size_t WSZ_E = 589824 * 2;        // one E x E bf16 weight (packed, same size)
  u16* w_all = (u16*)ws;                  // rq,rk,rv | ro | cq,ck,cv | co | f1 | f2
  u16* w_rqkv = w_all;
  u16* w_ro   = (u16*)(ws + 3 * WSZ_E);
  u16* w_cqkv = (u16*)(ws + 4 * WSZ_E);
  u16* w_co   = (u16*)(ws + 7 * WSZ_E);
  u16* w_f1   = (u16*)(ws + 8 * WSZ_E);                 // 4,718,592 B
  u16* w_f2   = (u16*)(ws + 8 * WSZ_E + 4718592);       // 4,718,592 B
  size_t off = 8 * WSZ_E + 2 * 4718592;                 // 18,874,368

  const bool xf32 = ws_size >= 147849216ULL;            // f32 residual if it fits
  char* x_cur = ws + off;                               // f32 (50.3MB) or bf16 (25.2MB)
  off += xf32 ? 50331648 : 25165824;
  u16* qb = (u16*)(ws + off); off += 25165824;
  u16* kb = (u16*)(ws + off); off += 25165824;
  u16* vb = (u16*)(ws + off); off += 25165824;
  u16* probsb = (u16*)(ws + off); off += 1048576;       // bf16 row probs (packed per head)
  float* qkvb_row = (float*)(ws + off); off += 9216;    // [2304] f32
  float* qkvb_col = (float*)(ws + off); off += 9216;

  u16* vt     = qb;            // row-attn V^T (packed) overlays qb (free after logits)
  u16* ctx1   = kb;            // row-attn context (packed) overlays kb
  u16* hidden = qb;            // FFN hidden chunk (packed, 50.3MB) overlays qb+kb
  u16* xn3    = vb;            // stage-3 LN output (packed) overlays vb

  // ---- d_out layout + d_out-as-scratch ----
  float* out_x  = (float*)d_out;            // 12,582,912 f32 (free until final fc2)
  float* out_rp = out_x + 12582912;         // row_probs [8,1,256,256] f32
  float* out_cp = out_x + 13107200;         // col_probs [8,256,1,64,64] f32
  u16* xn   = (u16*)out_x;                  // LN out (stages 1,2, packed), lower half
  u16* ctx2 = (u16*)((char*)out_x + 25165824);  // col-attn context (packed), upper half
  float* part = out_x;                      // split-K logits partials (33.5MB)

  const dim3 blk(256);

  // ---- weight conversion (one dispatch, packed) + bias packs ----
  CvtArgs ca;
  ca.src[0] = rq_w; ca.src[1] = rk_w; ca.src[2] = rv_w; ca.src[3] = ro_w;
  ca.src[4] = cq_w; ca.src[5] = ck_w; ca.src[6] = cv_w; ca.src[7] = co_w;
  ca.src[8] = f1_w; ca.src[9] = f2_w;
  for (int i = 0; i < 10; ++i) ca.scale[i] = 1.f;
  ca.scale[0] = s_row; ca.scale[4] = s_col;
  cvt_all<<<9216, blk, 0, stream>>>(ca, w_all);
  bias_pack<<<9, blk, 0, stream>>>(rq_b, rk_b, rv_b, s_row, qkvb_row);
  bias_pack<<<9, blk, 0, stream>>>(cq_b, ck_b, cv_b, s_col, qkvb_col);

  // ---- Stage 1: row attention ----
  ln_kernel<true><<<4096, blk, 0, stream>>>(x_in, lnr_w, lnr_b, xn);
  gemm_bt<0, 8, 1, 1, 1><<<dim3(128, 18, 1), blk, 0, stream>>>(xn, w_rqkv, qkvb_row, nullptr, qb, 768, 24, 24, 0, 0, 0, 768, 0, 1.f);
  // split-K logits: q/k row-major -> old path (z-batched, no swizzle)
  gemm_bt<2, 1, 0, 0, 0><<<dim3(2, 2, 128), blk, 0, stream>>>(qb, kb, nullptr, nullptr, part, 384, 0, 0, 0, 0, 65536LL, 256, 0, 1.f);
  softmax_row<<<512, blk, 0, stream>>>(part, out_rp, probsb);
  pack_vt<<<dim3(4, 64, 8), blk, 0, stream>>>(vb, vt);
  gemm_bt<0, 7, 1, 1, 0><<<dim3(2, 48, 8), blk, 0, stream>>>(probsb, vt, nullptr, nullptr, ctx1, 256, 8, 8, 65536LL, 1572864LL, 0, 0, 0, 1.f);
  if (xf32)
    gemm_bt<0, 3, 1, 1, 1><<<dim3(128, 6, 1), blk, 0, stream>>>(ctx1, w_ro, ro_b, x_in, x_cur, 768, 24, 24, 0, 0, 0, 768, 0, 1.f);
  else
    gemm_bt<0, 4, 1, 1, 1><<<dim3(128, 6, 1), blk, 0, stream>>>(ctx1, w_ro, ro_b, x_in, x_cur, 768, 24, 24, 0, 0, 0, 768, 0, 1.f);

  // ---- Stage 2: column attention ----
  if (xf32) ln_kernel<true><<<4096, blk, 0, stream>>>(x_cur, lnc_w, lnc_b, xn);
  else      ln_kernel<false><<<4096, blk, 0, stream>>>(x_cur, lnc_w, lnc_b, xn);
  gemm_bt<0, 8, 1, 1, 1><<<dim3(128, 18, 1), blk, 0, stream>>>(xn, w_cqkv, qkvb_col, nullptr, qb, 768, 24, 24, 0, 0, 0, 768, 0, 1.f);
  col_attn<<<dim3(256, 8), blk, 0, stream>>>(qb, kb, vb, out_cp, ctx2);
  if (xf32)
    gemm_bt<0, 3, 1, 1, 1><<<dim3(128, 6, 1), blk, 0, stream>>>(ctx2, w_co, co_b, x_cur, x_cur, 768, 24, 24, 0, 0, 0, 768, 0, 1.f);
  else
    gemm_bt<0, 4, 1, 1, 1><<<dim3(128, 6, 1), blk, 0, stream>>>(ctx2, w_co, co_b, x_cur, x_cur, 768, 24, 24, 0, 0, 0, 768, 0, 1.f);

  // ---- Stage 3: FFN (F chunked 2x1536 so hidden fits qb+kb) ----
  if (xf32) ln_kernel<true><<<4096, blk, 0, stream>>>(x_cur, lnf_w, lnf_b, xn3);
  else      ln_kernel<false><<<4096, blk, 0, stream>>>(x_cur, lnf_w, lnf_b, xn3);
  // chunk 0 (hidden written packed with NKT = 1536/32 = 48)
  gemm_bt<0, 2, 1, 1, 1><<<dim3(128, 12, 1), blk, 0, stream>>>(xn3, w_f1, f1_b, nullptr, hidden, 768, 24, 24, 0, 0, 0, 1536, 0, 1.f);
  gemm_bt<0, 3, 1, 1, 1><<<dim3(128, 6, 1), blk, 0, stream>>>(hidden, w_f2, f2_b, x_cur, out_x, 1536, 48, 96, 0, 0, 0, 768, 0, 1.f);
  // chunk 1 (accumulate into out_x; packed f2 addressed via bkt0=48)
  gemm_bt<0, 2, 1, 1, 1><<<dim3(128, 12, 1), blk, 0, stream>>>(xn3, w_f1 + 1536 * 768, f1_b + 1536, nullptr, hidden, 768, 24, 24, 0, 0, 0, 1536, 0, 1.f);
  gemm_bt<0, 3, 1, 1, 1><<<dim3(128, 6, 1), blk, 0, stream>>>(hidden, w_f2, nullptr, out_x, out_x, 1536, 48, 96, 0, 0, 0, 768, 48, 1.f);
}

// Round 20
// 574.254 us; speedup vs baseline: 1.0312x; 1.0312x over previous
//
#include <hip/hip_runtime.h>
#include <cstdint>

typedef unsigned short u16;
typedef __attribute__((ext_vector_type(8))) short short8;   // 8 x bf16 (4 VGPR)
typedef __attribute__((ext_vector_type(4))) short short4v;  // 4 x bf16
typedef __attribute__((ext_vector_type(4))) float floatx4;  // MFMA acc / float4

#define DEV __device__ __forceinline__

DEV float bf2f(u16 u) { union { uint32_t i; float f; } w; w.i = ((uint32_t)u) << 16; return w.f; }
DEV u16 f2bf(float f) {
  union { float f; uint32_t i; } w; w.f = f;
  uint32_t x = w.i;
  return (u16)((x + 0x7fffu + ((x >> 16) & 1u)) >> 16);  // RNE
}

// packed chunk-major element offset: tile(row>>7, k>>5) of 128x32, 4096 elems,
// inner [c=(k>>3)&3][row&127][k&7]  (r10-proven conflict-free for MFMA frags)
DEV size_t poff(int row, int k, int nkt) {
  return ((size_t)((row >> 7) * nkt + (k >> 5))) * 4096 +
         (size_t)(((k >> 3) & 3) * 1024 + (row & 127) * 8 + (k & 7));
}

// fast exact-gelu: A&S 7.1.26 erf approx, |err|<=1.5e-7, branchless
DEV float fast_gelu(float x) {
  const float y = x * 0.70710678118f;
  const float ay = fabsf(y);
  const float t = 1.f / (1.f + 0.3275911f * ay);
  const float poly = t * (0.254829592f + t * (-0.284496736f +
                     t * (1.421413741f + t * (-1.453152027f + t * 1.061405429f))));
  const float er = 1.f - poly * __expf(-y * y);
  const float erf_y = __builtin_copysignf(er, y);
  return 0.5f * x * (1.f + erf_y);
}

// async global->LDS, 16B per lane. LDS dest must be wave-uniform base; HW adds lane*16.
DEV void async_copy16(const u16* g, u16* l) {
  __builtin_amdgcn_global_load_lds(
      (const __attribute__((address_space(1))) void*)(uintptr_t)g,
      (__attribute__((address_space(3))) void*)(uint32_t)(uintptr_t)l,
      16, 0, 0);
}

// ---------------- fused f32 -> bf16 weight convert, PACKED chunk-major ----------------
struct CvtArgs {
  const float* src[10];
  float scale[10];
};
__global__ __launch_bounds__(256) void cvt_all(CvtArgs a, u16* __restrict__ dst) {
  const size_t e = ((size_t)blockIdx.x * 256 + threadIdx.x) * 4;  // packed dest offset
  if (e >= 9437184) return;
  int reg, N, K;
  size_t base;
  if (e < 4718592) { reg = (int)(e / 589824); base = (size_t)reg * 589824; N = 768; K = 768; }
  else if (e < 7077888) { reg = 8; base = 4718592; N = 3072; K = 768; }
  else { reg = 9; base = 7077888; N = 768; K = 3072; }
  const int NKT = K >> 5;
  const size_t r = e - base;
  const int tile = (int)(r >> 12);
  const int nt = tile / NKT, kt = tile - nt * NKT;
  const int rem = (int)(r & 4095);
  const int c = rem >> 10, row = (rem >> 3) & 127, j = rem & 7;  // j in {0,4}
  const int n = nt * 128 + row, k = kt * 32 + c * 8 + j;
  const float sc = a.scale[reg];
  floatx4 f = *(const floatx4*)(a.src[reg] + (size_t)n * K + k);
  short4v o;
#pragma unroll
  for (int q = 0; q < 4; ++q) o[q] = (short)f2bf(f[q] * sc);
  *(short4v*)(dst + e) = o;
}

// pack q/k/v biases into one [2304] f32 buffer per stage, q part pre-scaled
__global__ __launch_bounds__(256) void bias_pack(const float* __restrict__ qb,
                                                 const float* __restrict__ kb,
                                                 const float* __restrict__ vb,
                                                 float sq, float* __restrict__ out) {
  const int i = blockIdx.x * 256 + threadIdx.x;
  if (i >= 2304) return;
  const int buf = i / 768, c = i - buf * 768;
  out[i] = buf == 0 ? qb[c] * sq : (buf == 1 ? kb[c] : vb[c]);
}

// ---------------- LayerNorm: 4 rows/block, PACKED out via LDS re-staging ----------------
template<bool INF32>
__global__ __launch_bounds__(256) void ln_kernel(const void* __restrict__ in,
                                                 const float* __restrict__ w,
                                                 const float* __restrict__ b,
                                                 u16* __restrict__ out) {
  __shared__ u16 S[4][768];
  const int wid = threadIdx.x >> 6, lane = threadIdx.x & 63;
  const int row0 = blockIdx.x * 4;
  const int row = row0 + wid;  // 16384 rows
  const size_t base = (size_t)row * 768;
  float v[12];
#pragma unroll
  for (int p = 0; p < 3; ++p) {
    const int e = p * 256 + lane * 4;
    if constexpr (INF32) {
      floatx4 f = *(const floatx4*)((const float*)in + base + e);
#pragma unroll
      for (int j = 0; j < 4; ++j) v[p * 4 + j] = f[j];
    } else {
      short4v u = *(const short4v*)((const u16*)in + base + e);
#pragma unroll
      for (int j = 0; j < 4; ++j) v[p * 4 + j] = bf2f((u16)u[j]);
    }
  }
  float s = 0.f, sq = 0.f;
#pragma unroll
  for (int i = 0; i < 12; ++i) { s += v[i]; sq += v[i] * v[i]; }
#pragma unroll
  for (int m = 1; m < 64; m <<= 1) { s += __shfl_xor(s, m); sq += __shfl_xor(sq, m); }
  const float mean = s * (1.f / 768.f);
  const float var = sq * (1.f / 768.f) - mean * mean;
  const float rstd = rsqrtf(var + 1e-5f);
#pragma unroll
  for (int p = 0; p < 3; ++p) {
    const int e = p * 256 + lane * 4;
    floatx4 wv = *(const floatx4*)(w + e);
    floatx4 bv = *(const floatx4*)(b + e);
    short4v o;
#pragma unroll
    for (int j = 0; j < 4; ++j) {
      float y = (v[p * 4 + j] - mean) * rstd * wv[j] + bv[j];
      o[j] = (short)f2bf(y);
    }
    *(short4v*)&S[wid][e] = o;
  }
  __syncthreads();
  const int t = threadIdx.x;
  {
    const int ro = t & 3, c = t >> 2;                     // c 0..63
    *(short8*)(out + poff(row0 + ro, c * 8, 24)) = *(const short8*)&S[ro][c * 8];
  }
  if (t < 128) {
    const int idx = 256 + t;
    const int ro = idx & 3, c = idx >> 2;                 // c 64..95
    *(short8*)(out + poff(row0 + ro, c * 8, 24)) = *(const short8*)&S[ro][c * 8];
  }
}

// ---------------- GEMM: 128x128, r15/r17/r19 proven ----------------
// SWZ=1 (requires nwg%8==0, grid.z==1): bijective chunked XCD remap (T1).
// EPI: 1 f32=acc | 2 PACKED bf16=gelu(acc+bz) | 3 f32=resf32+acc+bz
//      4 bf16=resf32+acc+bz | 5 f32=resbf16+acc+bz | 6 bf16=resbf16+acc+bz
//      7 PACKED bf16 scatter (row-attn PV ctx) | 8 merged-QKV split write
template<int AMODE, int AP, int BP>
DEV void stage_tile(const u16* __restrict__ Asrc, const u16* __restrict__ Bsrc,
                    int m0, int n0, int lda, int ldb, int kk0, int ktAbs, int t,
                    u16* ldsA, u16* ldsB) {
  const int wid = t >> 6, lane = t & 63;
  const int col = (((t & 3) ^ ((t >> 2) & 3)) << 3);
#pragma unroll
  for (int i = 0; i < 2; ++i) {
    const int slot = i * 4 + wid;
    const int r = i * 64 + (t >> 2);
    const int kk = kk0 + col;
    if constexpr (AP) {
      async_copy16(Asrc + (size_t)ktAbs * 4096 + slot * 512 + lane * 8, ldsA + slot * 512);
    } else {
      const u16* ga;
      if constexpr (AMODE == 0) {
        ga = Asrc + (size_t)(m0 + r) * lda + kk;
      } else {
        const int r96 = kk / 96, d = kk - r96 * 96;  // 8|96: chunk never crosses r96
        ga = Asrc + (size_t)r96 * 196608 + (size_t)(m0 + r) * 768 + d;
      }
      async_copy16(ga, ldsA + i * 2048 + wid * 512);
    }
    if constexpr (BP) {
      async_copy16(Bsrc + (size_t)ktAbs * 4096 + slot * 512 + lane * 8, ldsB + slot * 512);
    } else {
      const u16* gb;
      if constexpr (AMODE == 0) {
        gb = Bsrc + (size_t)(n0 + r) * ldb + kk;
      } else {
        const int r96 = kk / 96, d = kk - r96 * 96;
        gb = Bsrc + (size_t)r96 * 196608 + (size_t)(n0 + r) * 768 + d;
      }
      async_copy16(gb, ldsB + i * 2048 + wid * 512);
    }
  }
}

template<int AMODE, int EPI, int AP, int BP, int SWZ>
__global__ __launch_bounds__(256) void gemm_bt(
    const u16* __restrict__ A, const u16* __restrict__ B,
    const float* __restrict__ bias, const void* __restrict__ res,
    void* __restrict__ out, int K, int lda, int ldb,
    long long aBatch, long long bBatch, long long outBatch, int ldc, int bkt0,
    float scale) {
  __shared__ u16 lds[3 * 8192];  // 3 x (A 128x32 + B 128x32) = 48KB
  const int t = threadIdx.x;
  const int z = blockIdx.z;
  int bx = blockIdx.x, by = blockIdx.y;
  if constexpr (SWZ) {
    const int nwg = gridDim.x * gridDim.y;
    const int bid = by * gridDim.x + bx;
    const int work = (bid & 7) * (nwg >> 3) + (bid >> 3);  // bijective (nwg%8==0)
    bx = work / gridDim.y;                                 // x contiguous per XCD
    by = work - bx * gridDim.y;
  }
  const int m0 = bx * 128, n0 = by * 128;
  const u16* Ab;
  const u16* Bb;
  int koff = 0;
  if constexpr (AMODE == 0) { Ab = A + (size_t)z * aBatch; Bb = B + (size_t)z * bBatch; }
  else { const int h = z >> 4; Ab = A + h * 96; Bb = B + h * 96; koff = (z & 15) * 384; }

  const u16* Astage;
  const u16* Bstage;
  if constexpr (AP) Astage = Ab + ((size_t)((m0 >> 7) * lda)) * 4096;
  else Astage = Ab;
  if constexpr (BP) Bstage = Bb + ((size_t)((n0 >> 7) * ldb + bkt0)) * 4096;
  else Bstage = Bb;

  const int wid = t >> 6, lane = t & 63;
  const int wr = wid >> 1, wc = wid & 1;
  const int lrow = lane & 15, lhi = lane >> 4;
  const int swl = lrow & 3;

  floatx4 acc[4][4];
#pragma unroll
  for (int i = 0; i < 4; ++i)
#pragma unroll
    for (int j = 0; j < 4; ++j) acc[i][j] = (floatx4){0.f, 0.f, 0.f, 0.f};

  const int NT = K >> 5;

  stage_tile<AMODE, AP, BP>(Astage, Bstage, m0, n0, lda, ldb, koff, 0, t, lds, lds + 4096);
  if (NT > 1)
    stage_tile<AMODE, AP, BP>(Astage, Bstage, m0, n0, lda, ldb, koff + 32, 1, t,
                              lds + 8192, lds + 8192 + 4096);
  if (NT > 2) asm volatile("s_waitcnt vmcnt(4)" ::: "memory");
  else        asm volatile("s_waitcnt vmcnt(0)" ::: "memory");
  __builtin_amdgcn_s_barrier();
  asm volatile("" ::: "memory");

  int cur = 0, nxt = 2;
  for (int kt = 0; kt < NT; ++kt) {
    const bool more = (kt + 2) < NT;
    if (more)
      stage_tile<AMODE, AP, BP>(Astage, Bstage, m0, n0, lda, ldb, koff + (kt + 2) * 32,
                                kt + 2, t, lds + nxt * 8192, lds + nxt * 8192 + 4096);

    const u16* lA = lds + cur * 8192;
    const u16* lB = lA + 4096;
    short8 af[4], bfr[4];
#pragma unroll
    for (int mi = 0; mi < 4; ++mi) {
      if constexpr (AP)
        af[mi] = *(const short8*)&lA[lhi * 1024 + (wr * 64 + mi * 16 + lrow) * 8];
      else
        af[mi] = *(const short8*)&lA[(wr * 64 + mi * 16 + lrow) * 32 + ((lhi ^ swl) << 3)];
    }
#pragma unroll
    for (int ni = 0; ni < 4; ++ni) {
      if constexpr (BP)
        bfr[ni] = *(const short8*)&lB[lhi * 1024 + (wc * 64 + ni * 16 + lrow) * 8];
      else
        bfr[ni] = *(const short8*)&lB[(wc * 64 + ni * 16 + lrow) * 32 + ((lhi ^ swl) << 3)];
    }

    __builtin_amdgcn_s_setprio(1);
#pragma unroll
    for (int mi = 0; mi < 4; ++mi)
#pragma unroll
      for (int ni = 0; ni < 4; ++ni)
        acc[mi][ni] = __builtin_amdgcn_mfma_f32_16x16x32_bf16(af[mi], bfr[ni], acc[mi][ni], 0, 0, 0);
    __builtin_amdgcn_s_setprio(0);

    if (kt + 1 < NT) {
      if (more) asm volatile("s_waitcnt vmcnt(4)" ::: "memory");
      else      asm volatile("s_waitcnt vmcnt(0)" ::: "memory");
      __builtin_amdgcn_s_barrier();
      asm volatile("" ::: "memory");
    }
    cur = (cur == 2) ? 0 : cur + 1;
    nxt = (nxt == 2) ? 0 : nxt + 1;
  }

  const int mbase = m0 + wr * 64;
  const int nbase = n0 + wc * 64;
#pragma unroll
  for (int mi = 0; mi < 4; ++mi) {
#pragma unroll
    for (int ni = 0; ni < 4; ++ni) {
      const int n = nbase + ni * 16 + lrow;
      float bz = 0.f;
      if constexpr (EPI != 1 && EPI != 7) { if (bias) bz = bias[n]; }
#pragma unroll
      for (int r4 = 0; r4 < 4; ++r4) {
        const int m = mbase + mi * 16 + lhi * 4 + r4;
        const float val = acc[mi][ni][r4];
        if constexpr (EPI == 1) {
          ((float*)out)[(size_t)z * outBatch + (size_t)m * ldc + n] = val;
        } else if constexpr (EPI == 2) {
          ((u16*)out)[poff(m, n, ldc >> 5)] = f2bf(fast_gelu(val + bz));
        } else if constexpr (EPI == 3) {
          const float r = ((const float*)res)[(size_t)m * ldc + n];
          ((float*)out)[(size_t)m * ldc + n] = r + val + bz;
        } else if constexpr (EPI == 4) {
          const float r = ((const float*)res)[(size_t)m * ldc + n];
          ((u16*)out)[(size_t)m * ldc + n] = f2bf(r + val + bz);
        } else if constexpr (EPI == 5) {
          const float r = bf2f(((const u16*)res)[(size_t)m * ldc + n]);
          ((float*)out)[(size_t)m * ldc + n] = r + val + bz;
        } else if constexpr (EPI == 6) {
          const float r = bf2f(((const u16*)res)[(size_t)m * ldc + n]);
          ((u16*)out)[(size_t)m * ldc + n] = f2bf(r + val + bz);
        } else if constexpr (EPI == 7) {
          const int rr = n / 96, d = n - rr * 96;
          ((u16*)out)[poff(rr * 256 + m, z * 96 + d, 24)] = f2bf(val);
        } else if constexpr (EPI == 8) {
          const int buf = n / 768, col = n - buf * 768;
          ((u16*)out)[(size_t)buf * 12582912 + (size_t)m * 768 + col] = f2bf(val + bz);
        }
      }
    }
  }
}

// ---------------- row softmax fused with split-K reduce; PACKED probsb ----------------
__global__ __launch_bounds__(256) void softmax_row(const float* __restrict__ part,
                                                   float* __restrict__ probs_f,
                                                   u16* __restrict__ probs_b) {
  const int wid = threadIdx.x >> 6, lane = threadIdx.x & 63;
  const int row = blockIdx.x * 4 + wid;
  const int h = row >> 8, i = row & 255;
  const size_t base = (size_t)h * 16 * 65536 + (size_t)i * 256 + lane * 4;
  floatx4 v = (floatx4){0.f, 0.f, 0.f, 0.f};
#pragma unroll
  for (int s16 = 0; s16 < 16; ++s16) {
    floatx4 p = *(const floatx4*)(part + base + (size_t)s16 * 65536);
#pragma unroll
    for (int j = 0; j < 4; ++j) v[j] += p[j];
  }
  float mx = fmaxf(fmaxf(v[0], v[1]), fmaxf(v[2], v[3]));
#pragma unroll
  for (int m = 1; m < 64; m <<= 1) mx = fmaxf(mx, __shfl_xor(mx, m));
  float e[4], s = 0.f;
#pragma unroll
  for (int j = 0; j < 4; ++j) { e[j] = __expf(v[j] - mx); s += e[j]; }
#pragma unroll
  for (int m = 1; m < 64; m <<= 1) s += __shfl_xor(s, m);
  const float inv = 1.f / s;
  floatx4 of;
  short4v ob;
#pragma unroll
  for (int j = 0; j < 4; ++j) {
    const float p = e[j] * inv;
    of[j] = p;
    ob[j] = (short)f2bf(p);
  }
  *(floatx4*)(probs_f + (size_t)row * 256 + lane * 4) = of;
  *(short4v*)(probs_b + (size_t)h * 65536 + poff(i, lane * 4, 8)) = ob;
}

// ---------------- pack V^T for row-attn PV, PACKED chunk-major ----------------
__global__ __launch_bounds__(256) void pack_vt(const u16* __restrict__ v, u16* __restrict__ vt) {
  __shared__ u16 S[64][104];  // [j][d], padded
  const int jb = blockIdx.x, r = blockIdx.y, h = blockIdx.z;
  const int t = threadIdx.x;
#pragma unroll
  for (int p = 0; p < 3; ++p) {
    const int cid = t + p * 256;
    const int j = cid / 12, ch = cid - j * 12;
    short8 x = *(const short8*)&v[((size_t)(r * 256 + jb * 64 + j)) * 768 + h * 96 + ch * 8];
    *(short8*)&S[j][ch * 8] = x;
  }
  __syncthreads();
#pragma unroll
  for (int p = 0; p < 3; ++p) {
    const int cid = t + p * 256;
    const int d = cid / 8, cj = cid - d * 8;
    u16 tmp[8];
#pragma unroll
    for (int m = 0; m < 8; ++m) tmp[m] = S[cj * 8 + m][d];
    const int row_t = r * 96 + d;
    const int k = jb * 64 + cj * 8;
    *(short8*)&vt[(size_t)h * 1572864 + poff(row_t, k, 8)] = *(short8*)tmp;
  }
}

// ---------------- fused column attention: one block per (c, h); PACKED ctx ----------
__global__ __launch_bounds__(256) void col_attn(const u16* __restrict__ q,
                                                const u16* __restrict__ k,
                                                const u16* __restrict__ v,
                                                float* __restrict__ probs,
                                                u16* __restrict__ ctx) {
  __shared__ u16 qs[64][104];
  __shared__ u16 ks[64][104];
  __shared__ u16 vt[96][72];
  __shared__ u16 ps[64][72];
  const int c = blockIdx.x, h = blockIdx.y;
  const int t = threadIdx.x;
#pragma unroll
  for (int p = 0; p < 3; ++p) {
    const int cid = t + p * 256;
    const int i = cid / 12, ch = cid - i * 12;
    const size_t g = ((size_t)(i * 256 + c)) * 768 + h * 96 + ch * 8;
    short8 qv = *(const short8*)(q + g);
    short8 kv = *(const short8*)(k + g);
    short8 vv = *(const short8*)(v + g);
    *(short8*)&qs[i][ch * 8] = qv;
    *(short8*)&ks[i][ch * 8] = kv;
#pragma unroll
    for (int m = 0; m < 8; ++m) vt[ch * 8 + m][i] = (u16)vv[m];
  }
  __syncthreads();
  const int lane = t & 63, wid = t >> 6;
  const int lrow = lane & 15, lhi = lane >> 4;

  floatx4 s[4];
#pragma unroll
  for (int nj = 0; nj < 4; ++nj) s[nj] = (floatx4){0.f, 0.f, 0.f, 0.f};
#pragma unroll
  for (int kk = 0; kk < 3; ++kk) {
    short8 a = *(const short8*)&qs[wid * 16 + lrow][kk * 32 + lhi * 8];
#pragma unroll
    for (int nj = 0; nj < 4; ++nj) {
      short8 bb = *(const short8*)&ks[nj * 16 + lrow][kk * 32 + lhi * 8];
      s[nj] = __builtin_amdgcn_mfma_f32_16x16x32_bf16(a, bb, s[nj], 0, 0, 0);
    }
  }
  const size_t pb = ((size_t)(h * 256 + c)) * 4096;
#pragma unroll
  for (int r4 = 0; r4 < 4; ++r4) {
    float mx = fmaxf(fmaxf(s[0][r4], s[1][r4]), fmaxf(s[2][r4], s[3][r4]));
    mx = fmaxf(mx, __shfl_xor(mx, 1));
    mx = fmaxf(mx, __shfl_xor(mx, 2));
    mx = fmaxf(mx, __shfl_xor(mx, 4));
    mx = fmaxf(mx, __shfl_xor(mx, 8));
    float e[4], sum = 0.f;
#pragma unroll
    for (int nj = 0; nj < 4; ++nj) { e[nj] = __expf(s[nj][r4] - mx); sum += e[nj]; }
    sum += __shfl_xor(sum, 1);
    sum += __shfl_xor(sum, 2);
    sum += __shfl_xor(sum, 4);
    sum += __shfl_xor(sum, 8);
    const float inv = 1.f / sum;
    const int i = wid * 16 + lhi * 4 + r4;
#pragma unroll
    for (int nj = 0; nj < 4; ++nj) {
      const float pv = e[nj] * inv;
      const int j = nj * 16 + lrow;
      probs[pb + (size_t)i * 64 + j] = pv;
      ps[i][j] = f2bf(pv);
    }
  }
  __syncthreads();
  floatx4 o[6];
#pragma unroll
  for (int df = 0; df < 6; ++df) o[df] = (floatx4){0.f, 0.f, 0.f, 0.f};
#pragma unroll
  for (int k2 = 0; k2 < 2; ++k2) {
    short8 a = *(const short8*)&ps[wid * 16 + lrow][k2 * 32 + lhi * 8];
#pragma unroll
    for (int df = 0; df < 6; ++df) {
      short8 bb = *(const short8*)&vt[df * 16 + lrow][k2 * 32 + lhi * 8];
      o[df] = __builtin_amdgcn_mfma_f32_16x16x32_bf16(a, bb, o[df], 0, 0, 0);
    }
  }
#pragma unroll
  for (int df = 0; df < 6; ++df)
#pragma unroll
    for (int r4 = 0; r4 < 4; ++r4) {
      const int i = wid * 16 + lhi * 4 + r4;
      const int d = df * 16 + lrow;
      ctx[poff(i * 256 + c, h * 96 + d, 24)] = f2bf(o[df][r4]);  // packed ctx2
    }
}

// ---------------- host launch ----------------
extern "C" void kernel_launch(void* const* d_in, const int* in_sizes, int n_in,
                              void* d_out, int out_size, void* d_ws, size_t ws_size,
                              hipStream_t stream) {
  const float* x_in  = (const float*)d_in[0];
  const float* lnr_w = (const float*)d_in[1];
  const float* lnr_b = (const float*)d_in[2];
  const float* rq_w  = (const float*)d_in[3];
  const float* rq_b  = (const float*)d_in[4];
  const float* rk_w  = (const float*)d_in[5];
  const float* rk_b  = (const float*)d_in[6];
  const float* rv_w  = (const float*)d_in[7];
  const float* rv_b  = (const float*)d_in[8];
  const float* ro_w  = (const float*)d_in[9];
  const float* ro_b  = (const float*)d_in[10];
  const float* lnc_w = (const float*)d_in[11];
  const float* lnc_b = (const float*)d_in[12];
  const float* cq_w  = (const float*)d_in[13];
  const float* cq_b  = (const float*)d_in[14];
  const float* ck_w  = (const float*)d_in[15];
  const float* ck_b  = (const float*)d_in[16];
  const float* cv_w  = (const float*)d_in[17];
  const float* cv_b  = (const float*)d_in[18];
  const float* co_w  = (const float*)d_in[19];
  const float* co_b  = (const float*)d_in[20];
  const float* lnf_w = (const float*)d_in[21];
  const float* lnf_b = (const float*)d_in[22];
  const float* f1_w  = (const float*)d_in[23];
  const float* f1_b  = (const float*)d_in[24];
  const float* f2_w  = (const float*)d_in[25];
  const float* f2_b  = (const float*)d_in[26];

  const float s_row = 0.0127577591f;  // (96^-0.5)/8
  const float s_col = 0.1020620726f;  // 96^-0.5

  // ---- ws layout (x_cur now bf16: residual traffic halved) ----
  char* ws = (char*)d_ws;
  const size_t WSZ_E = 589824 * 2;        // one E x E bf16 weight (packed, same size)
  u16* w_all = (u16*)ws;                  // rq,rk,rv | ro | cq,ck,cv | co | f1 | f2
  u16* w_rqkv = w_all;
  u16* w_ro   = (u16*)(ws + 3 * WSZ_E);
  u16* w_cqkv = (u16*)(ws + 4 * WSZ_E);
  u16* w_co   = (u16*)(ws + 7 * WSZ_E);
  u16* w_f1   = (u16*)(ws + 8 * WSZ_E);                 // 4,718,592 B
  u16* w_f2   = (u16*)(ws + 8 * WSZ_E + 4718592);       // 4,718,592 B
  size_t off = 8 * WSZ_E + 2 * 4718592;                 // 18,874,368

  u16* x_cur = (u16*)(ws + off); off += 25165824;       // bf16 residual (16384x768)
  u16* qb = (u16*)(ws + off); off += 25165824;
  u16* kb = (u16*)(ws + off); off += 25165824;
  u16* vb = (u16*)(ws + off); off += 25165824;
  u16* probsb = (u16*)(ws + off); off += 1048576;       // bf16 row probs (packed per head)
  float* qkvb_row = (float*)(ws + off); off += 9216;    // [2304] f32
  float* qkvb_col = (float*)(ws + off); off += 9216;

  u16* vt     = qb;            // row-attn V^T (packed) overlays qb (free after logits)
  u16* ctx1   = kb;            // row-attn context (packed) overlays kb
  u16* hidden = qb;            // FFN hidden chunk (packed, 50.3MB) overlays qb+kb
  u16* xn3    = vb;            // stage-3 LN output (packed) overlays vb

  // ---- d_out layout + d_out-as-scratch ----
  float* out_x  = (float*)d_out;            // 12,582,912 f32 (free until final fc2)
  float* out_rp = out_x + 12582912;         // row_probs [8,1,256,256] f32
  float* out_cp = out_x + 13107200;         // col_probs [8,256,1,64,64] f32
  u16* xn   = (u16*)out_x;                  // LN out (stages 1,2, packed), lower half
  u16* ctx2 = (u16*)((char*)out_x + 25165824);  // col-attn context (packed), upper half
  float* part = out_x;                      // split-K logits partials (33.5MB)

  const dim3 blk(256);

  // ---- weight conversion (one dispatch, packed) + bias packs ----
  CvtArgs ca;
  ca.src[0] = rq_w; ca.src[1] = rk_w; ca.src[2] = rv_w; ca.src[3] = ro_w;
  ca.src[4] = cq_w; ca.src[5] = ck_w; ca.src[6] = cv_w; ca.src[7] = co_w;
  ca.src[8] = f1_w; ca.src[9] = f2_w;
  for (int i = 0; i < 10; ++i) ca.scale[i] = 1.f;
  ca.scale[0] = s_row; ca.scale[4] = s_col;
  cvt_all<<<9216, blk, 0, stream>>>(ca, w_all);
  bias_pack<<<9, blk, 0, stream>>>(rq_b, rk_b, rv_b, s_row, qkvb_row);
  bias_pack<<<9, blk, 0, stream>>>(cq_b, ck_b, cv_b, s_col, qkvb_col);

  // ---- Stage 1: row attention ----
  ln_kernel<true><<<4096, blk, 0, stream>>>(x_in, lnr_w, lnr_b, xn);
  gemm_bt<0, 8, 1, 1, 1><<<dim3(128, 18, 1), blk, 0, stream>>>(xn, w_rqkv, qkvb_row, nullptr, qb, 768, 24, 24, 0, 0, 0, 768, 0, 1.f);
  // split-K logits: q/k row-major -> old path (z-batched, no swizzle)
  gemm_bt<2, 1, 0, 0, 0><<<dim3(2, 2, 128), blk, 0, stream>>>(qb, kb, nullptr, nullptr, part, 384, 0, 0, 0, 0, 65536LL, 256, 0, 1.f);
  softmax_row<<<512, blk, 0, stream>>>(part, out_rp, probsb);
  pack_vt<<<dim3(4, 64, 8), blk, 0, stream>>>(vb, vt);
  gemm_bt<0, 7, 1, 1, 0><<<dim3(2, 48, 8), blk, 0, stream>>>(probsb, vt, nullptr, nullptr, ctx1, 256, 8, 8, 65536LL, 1572864LL, 0, 0, 0, 1.f);
  // ro: res = x_in (f32), out = x_cur (bf16)
  gemm_bt<0, 4, 1, 1, 1><<<dim3(128, 6, 1), blk, 0, stream>>>(ctx1, w_ro, ro_b, x_in, x_cur, 768, 24, 24, 0, 0, 0, 768, 0, 1.f);

  // ---- Stage 2: column attention ----
  ln_kernel<false><<<4096, blk, 0, stream>>>(x_cur, lnc_w, lnc_b, xn);
  gemm_bt<0, 8, 1, 1, 1><<<dim3(128, 18, 1), blk, 0, stream>>>(xn, w_cqkv, qkvb_col, nullptr, qb, 768, 24, 24, 0, 0, 0, 768, 0, 1.f);
  col_attn<<<dim3(256, 8), blk, 0, stream>>>(qb, kb, vb, out_cp, ctx2);
  // co: res = x_cur (bf16), out = x_cur (bf16)
  gemm_bt<0, 6, 1, 1, 1><<<dim3(128, 6, 1), blk, 0, stream>>>(ctx2, w_co, co_b, x_cur, x_cur, 768, 24, 24, 0, 0, 0, 768, 0, 1.f);

  // ---- Stage 3: FFN (F chunked 2x1536 so hidden fits qb+kb) ----
  ln_kernel<false><<<4096, blk, 0, stream>>>(x_cur, lnf_w, lnf_b, xn3);
  // chunk 0 (hidden written packed with NKT = 1536/32 = 48)
  gemm_bt<0, 2, 1, 1, 1><<<dim3(128, 12, 1), blk, 0, stream>>>(xn3, w_f1, f1_b, nullptr, hidden, 768, 24, 24, 0, 0, 0, 1536, 0, 1.f);
  // fc2 chunk 0: res = x_cur (bf16) -> f32 out_x
  gemm_bt<0, 5, 1, 1, 1><<<dim3(128, 6, 1), blk, 0, stream>>>(hidden, w_f2, f2_b, x_cur, out_x, 1536, 48, 96, 0, 0, 0, 768, 0, 1.f);
  // chunk 1 (accumulate into out_x; packed f2 addressed via bkt0=48)
  gemm_bt<0, 2, 1, 1, 1><<<dim3(128, 12, 1), blk, 0, stream>>>(xn3, w_f1 + 1536 * 768, f1_b + 1536, nullptr, hidden, 768, 24, 24, 0, 0, 0, 1536, 0, 1.f);
  gemm_bt<0, 3, 1, 1, 1><<<dim3(128, 6, 1), blk, 0, stream>>>(hidden, w_f2, nullptr, out_x, out_x, 1536, 48, 96, 0, 0, 0, 768, 48, 1.f);
}